// Round 1
// baseline (394.291 us; speedup 1.0000x reference)
//
#include <hip/hip_runtime.h>

typedef __attribute__((ext_vector_type(8))) short short8;
typedef __attribute__((ext_vector_type(4))) unsigned short ushort4v;
typedef __attribute__((ext_vector_type(4))) float f32x4;

#define SCALE_F 0.17677669529663687f  // 1/sqrt(32)

__device__ __forceinline__ unsigned short f2bf(float f){
  unsigned u = __builtin_bit_cast(unsigned, f);
  u += 0x7fffu + ((u >> 16) & 1u);          // RNE
  return (unsigned short)(u >> 16);
}
__device__ __forceinline__ float bf2f(unsigned short h){
  unsigned u = ((unsigned)h) << 16;
  return __builtin_bit_cast(float, u);
}

// ---------------------------------------------------------------------------
// LDS map (64 KiB total -> 2 blocks/CU):
//   [    0,16384) : ph1-2: x window bf16 [t=64][c=128] swizzled (rowstride 256B)
//                   ph3  : S bf16 [64][64] (0..8K), P bf16 [64][64] (8K..16K)
//   [16384,32768) : q bf16 [t=64][c=128] swz     -> ph4+: attn-out bf16 [t][c]
//   [32768,49152) : k bf16 [t=64][c=128] swz
//   [49152,65536) : v^T bf16 [c=128][t=64] swz (rowstride 128B)
// Swizzle: byte_col ^ ((row&7)<<4)  -- consistent on every read & write.
// ---------------------------------------------------------------------------

template<bool WSB>
__global__ void __launch_bounds__(256, 2)
swin_fused(const float* __restrict__ x, const float* __restrict__ qkvw_f,
           const float* __restrict__ projw_f, const float* __restrict__ projb,
           const float* __restrict__ btab, const unsigned short* __restrict__ wbf,
           float* __restrict__ out)
{
  __shared__ __align__(16) unsigned char sm[65536];
  const int tid  = threadIdx.x;
  const int lane = tid & 63, wv = tid >> 6;
  const int lr = lane & 15, lg = lane >> 4;

  // XCD-aware swizzle: 8192 blocks, 8 XCDs -> each XCD gets one contiguous
  // batch plane (bijective since 8192 % 8 == 0).
  const int bid = blockIdx.x;
  const int sw  = ((bid & 7) << 10) | (bid >> 3);
  const int b   = sw >> 10;
  const int wh  = (sw >> 5) & 31, ww = sw & 31;
  const int hb  = wh * 8 + 4, wb = ww * 8 + 4;   // +SHIFT: shifted-frame -> source coords
  const bool h31 = (wh == 31), w31 = (ww == 31);

  // ---- Phase 1: load x window (roll -4,-4) -> bf16 LDS [t][c] swizzled ----
  {
    const int t  = tid & 63;
    const int gh = (hb + (t >> 3)) & 255;
    const int gw = (wb + (t & 7)) & 255;
    const float* px = x + (((b * 128) << 16) + (gh << 8) + gw);
    const int c0b = (tid >> 6) * 8;
    #pragma unroll
    for (int it = 0; it < 4; ++it) {
      const int c0 = c0b + it * 32;
      const float* p = px + (c0 << 16);
      short8 v;
      #pragma unroll
      for (int cc = 0; cc < 8; ++cc) v[cc] = (short)f2bf(p[cc << 16]);
      *(short8*)(sm + t * 256 + ((2 * c0) ^ ((t & 7) << 4))) = v;
    }
  }
  __syncthreads();

  // ---- Phase 2: QKV = W * x^T  (D[o][t]; M=o 24 tiles, N=t 4, K=c 4) ----
  {
    short8 Bf[16];                      // x^T fragments, reused by all o-tiles
    #pragma unroll
    for (int nt = 0; nt < 4; ++nt)
      #pragma unroll
      for (int kk = 0; kk < 4; ++kk) {
        const int t = nt * 16 + lr;
        Bf[nt * 4 + kk] = *(short8*)(sm + t * 256 + ((64 * kk + 16 * lg) ^ ((t & 7) << 4)));
      }
    #pragma unroll
    for (int jj = 0; jj < 6; ++jj) {
      const int mt = wv + 4 * jj;       // wave gets o-tiles {wv, wv+4, ...}: 2q,2k,2v each
      const int orow = mt * 16 + lr;
      short8 Af[4];
      #pragma unroll
      for (int kk = 0; kk < 4; ++kk) {
        const int off = orow * 128 + kk * 32 + 8 * lg;
        if constexpr (WSB) {
          Af[kk] = *(const short8*)(wbf + off);
        } else {
          const float* p = qkvw_f + off;
          short8 r;
          #pragma unroll
          for (int e = 0; e < 8; ++e) r[e] = (short)f2bf(p[e]);
          Af[kk] = r;
        }
      }
      f32x4 acc[4];
      #pragma unroll
      for (int nt = 0; nt < 4; ++nt) {
        acc[nt] = (f32x4)(0.f);
        #pragma unroll
        for (int kk = 0; kk < 4; ++kk)
          acc[nt] = __builtin_amdgcn_mfma_f32_16x16x32_bf16(Af[kk], Bf[nt * 4 + kk], acc[nt], 0, 0, 0);
      }
      // epilogue: D rows o = mt*16 + 4*lg + r (4 consecutive), col t = nt*16+lr
      if (mt < 16) {                    // q or k: pack 4 consecutive channels -> b64
        const int base = (mt < 8) ? 16384 : 32768;
        const int c0 = ((mt & 7) * 16) + 4 * lg;
        #pragma unroll
        for (int nt = 0; nt < 4; ++nt) {
          const int t = nt * 16 + lr;
          ushort4v pk;
          #pragma unroll
          for (int r = 0; r < 4; ++r) pk[r] = f2bf(acc[nt][r]);
          *(ushort4v*)(sm + base + t * 256 + ((2 * c0) ^ ((t & 7) << 4))) = pk;
        }
      } else {                          // v: store transposed vT[c][t]
        const int c0 = (mt - 16) * 16 + 4 * lg;
        #pragma unroll
        for (int nt = 0; nt < 4; ++nt) {
          const int t = nt * 16 + lr;
          #pragma unroll
          for (int r = 0; r < 4; ++r) {
            const int c = c0 + r;
            *(unsigned short*)(sm + 49152 + c * 128 + ((2 * t) ^ ((c & 7) << 4))) = f2bf(acc[nt][r]);
          }
        }
      }
    }
  }
  __syncthreads();

  // ---- Phase 3: per-head attention; PV accumulates in VGPRs across heads ----
  f32x4 accpv[8];
  #pragma unroll
  for (int z = 0; z < 8; ++z) accpv[z] = (f32x4)(0.f);

  #pragma unroll
  for (int h = 0; h < 4; ++h) {
    // QK^T: wave wv owns key-column tile kt in [16*wv, 16*wv+16)
    {
      const int cb = 64 * h + 16 * lg;             // byte col into head-h slice
      const int ktc = wv * 16 + lr;
      const short8 kb = *(short8*)(sm + 32768 + ktc * 256 + (cb ^ ((ktc & 7) << 4)));
      const int ki = ktc >> 3, kj = ktc & 7;
      #pragma unroll
      for (int mt = 0; mt < 4; ++mt) {
        const int q = mt * 16 + lr;
        const short8 qa = *(short8*)(sm + 16384 + q * 256 + (cb ^ ((q & 7) << 4)));
        f32x4 sacc = __builtin_amdgcn_mfma_f32_16x16x32_bf16(qa, kb, (f32x4)(0.f), 0, 0, 0);
        #pragma unroll
        for (int r = 0; r < 4; ++r) {
          const int qrow = mt * 16 + 4 * lg + r;
          const int qi = qrow >> 3, qj = qrow & 7;
          float s = sacc[r] * SCALE_F;
          s += btab[((qi - ki + 7) * 15 + (qj - kj + 7)) * 4 + h];
          const bool bad = (h31 && ((qi >= 4) != (ki >= 4))) || (w31 && ((qj >= 4) != (kj >= 4)));
          s += bad ? -100.f : 0.f;
          *(unsigned short*)(sm + qrow * 128 + ((2 * ktc) ^ ((qrow & 7) << 4))) = f2bf(s);
        }
      }
    }
    __syncthreads();
    // softmax: 4 lanes per row (row = tid>>2), group-reduce via shfl_xor 1,2
    {
      const int srow = tid >> 2, sq = tid & 3;
      const int swz = (srow & 7) << 4;
      const short8 s0 = *(short8*)(sm + srow * 128 + ((sq * 32) ^ swz));
      const short8 s1 = *(short8*)(sm + srow * 128 + ((sq * 32 + 16) ^ swz));
      float v[16];
      #pragma unroll
      for (int e = 0; e < 8; ++e) { v[e] = bf2f((unsigned short)s0[e]); v[e + 8] = bf2f((unsigned short)s1[e]); }
      float mx = v[0];
      #pragma unroll
      for (int e = 1; e < 16; ++e) mx = fmaxf(mx, v[e]);
      mx = fmaxf(mx, __shfl_xor(mx, 1));
      mx = fmaxf(mx, __shfl_xor(mx, 2));
      float sum = 0.f;
      #pragma unroll
      for (int e = 0; e < 16; ++e) { v[e] = __expf(v[e] - mx); sum += v[e]; }
      sum += __shfl_xor(sum, 1);
      sum += __shfl_xor(sum, 2);
      const float inv = 1.f / sum;
      short8 p0, p1;
      #pragma unroll
      for (int e = 0; e < 8; ++e) { p0[e] = (short)f2bf(v[e] * inv); p1[e] = (short)f2bf(v[e + 8] * inv); }
      *(short8*)(sm + 8192 + srow * 128 + ((sq * 32) ^ swz)) = p0;        // P disjoint from S
      *(short8*)(sm + 8192 + srow * 128 + ((sq * 32 + 16) ^ swz)) = p1;
    }
    __syncthreads();
    // PV: wave wv owns query rows [16*wv, 16*wv+16); D[q][d]
    {
      const int q = wv * 16 + lr;
      const int qs_ = (q & 7) << 4;
      const short8 pa0 = *(short8*)(sm + 8192 + q * 128 + ((16 * lg) ^ qs_));
      const short8 pa1 = *(short8*)(sm + 8192 + q * 128 + ((64 + 16 * lg) ^ qs_));
      #pragma unroll
      for (int nd = 0; nd < 2; ++nd) {
        const int c = h * 32 + nd * 16 + lr;       // vT row = head channel
        const int cs = (c & 7) << 4;
        const short8 vb0 = *(short8*)(sm + 49152 + c * 128 + ((16 * lg) ^ cs));
        const short8 vb1 = *(short8*)(sm + 49152 + c * 128 + ((64 + 16 * lg) ^ cs));
        f32x4 a = accpv[h * 2 + nd];
        a = __builtin_amdgcn_mfma_f32_16x16x32_bf16(pa0, vb0, a, 0, 0, 0);
        a = __builtin_amdgcn_mfma_f32_16x16x32_bf16(pa1, vb1, a, 0, 0, 0);
        accpv[h * 2 + nd] = a;
      }
    }
    // no barrier needed: next QK writes S (0..8K) while laggards read P (8K..16K)
  }

  // ---- Phase 4: attn-out -> LDS (overlays q region; q fully consumed) ----
  {
    #pragma unroll
    for (int h = 0; h < 4; ++h)
      #pragma unroll
      for (int nd = 0; nd < 2; ++nd) {
        const int c = h * 32 + nd * 16 + lr;
        const f32x4 a = accpv[h * 2 + nd];
        #pragma unroll
        for (int r = 0; r < 4; ++r) {
          const int t = wv * 16 + 4 * lg + r;
          *(unsigned short*)(sm + 16384 + t * 256 + ((2 * c) ^ ((t & 7) << 4))) = f2bf(a[r]);
        }
      }
  }
  __syncthreads();

  // ---- Phase 5: proj (D[t][o]) + bias + store with roll(+4,+4) ----
  {
    short8 Aa[16];                       // attn-out fragments, reused by both o-tiles
    #pragma unroll
    for (int mt = 0; mt < 4; ++mt)
      #pragma unroll
      for (int kk = 0; kk < 4; ++kk) {
        const int t = mt * 16 + lr;
        Aa[mt * 4 + kk] = *(short8*)(sm + 16384 + t * 256 + ((64 * kk + 16 * lg) ^ ((t & 7) << 4)));
      }
    #pragma unroll
    for (int ntl = 0; ntl < 2; ++ntl) {
      const int nt = wv + 4 * ntl;
      const int o = nt * 16 + lr;
      short8 Bw[4];
      #pragma unroll
      for (int kk = 0; kk < 4; ++kk) {
        const int coff = kk * 32 + 8 * lg;
        if constexpr (WSB) {
          Bw[kk] = *(const short8*)(wbf + 49152 + o * 128 + coff);
        } else {
          const float* p = projw_f + o * 128 + coff;
          short8 r;
          #pragma unroll
          for (int e = 0; e < 8; ++e) r[e] = (short)f2bf(p[e]);
          Bw[kk] = r;
        }
      }
      const float pb = projb[o];
      #pragma unroll
      for (int mt = 0; mt < 4; ++mt) {
        f32x4 acc = (f32x4)(0.f);
        #pragma unroll
        for (int kk = 0; kk < 4; ++kk)
          acc = __builtin_amdgcn_mfma_f32_16x16x32_bf16(Aa[mt * 4 + kk], Bw[kk], acc, 0, 0, 0);
        // D rows t = mt*16 + 4*lg + r: 4 consecutive tokens = 4 consecutive w
        const int t0 = mt * 16 + 4 * lg;
        const int gh = (hb + (t0 >> 3)) & 255;
        const int gw0 = (wb + (t0 & 7)) & 255;   // mult of 4 -> 16B aligned, no wrap in run
        f32x4 ov;
        ov[0] = acc[0] + pb; ov[1] = acc[1] + pb; ov[2] = acc[2] + pb; ov[3] = acc[3] + pb;
        *(f32x4*)(out + (((b * 128 + o) << 16) + (gh << 8) + gw0)) = ov;
      }
    }
  }
}

// One-time (per launch) weight fp32 -> bf16 into workspace.
__global__ void prep_weights(const float* __restrict__ qw, const float* __restrict__ pw,
                             unsigned short* __restrict__ wsb)
{
  const int i = blockIdx.x * 256 + threadIdx.x;
  const int idx = i * 4;                        // 65536 elements total
  const float* src = (idx < 49152) ? (qw + idx) : (pw + (idx - 49152));
  f32x4 v = *(const f32x4*)src;
  ushort4v o;
  #pragma unroll
  for (int e = 0; e < 4; ++e) o[e] = f2bf(v[e]);
  *(ushort4v*)(wsb + idx) = o;
}

extern "C" void kernel_launch(void* const* d_in, const int* in_sizes, int n_in,
                              void* d_out, int out_size, void* d_ws, size_t ws_size,
                              hipStream_t stream) {
  const float* x     = (const float*)d_in[0];
  const float* qkvw  = (const float*)d_in[1];
  const float* projw = (const float*)d_in[2];
  const float* projb = (const float*)d_in[3];
  const float* btab  = (const float*)d_in[4];
  float* out = (float*)d_out;

  if (ws_size >= 131072) {
    unsigned short* wsb = (unsigned short*)d_ws;
    prep_weights<<<64, 256, 0, stream>>>(qkvw, projw, wsb);
    swin_fused<true><<<8192, 256, 0, stream>>>(x, qkvw, projw, projb, btab, wsb, out);
  } else {
    swin_fused<false><<<8192, 256, 0, stream>>>(x, qkvw, projw, projb, btab, nullptr, out);
  }
}